// Round 1
// baseline (289.309 us; speedup 1.0000x reference)
//
#include <hip/hip_runtime.h>
#include <hip/hip_bf16.h>

// Problem constants
#define B_ 4
#define N_ 4096
#define PD_ 1024
#define D_ 16
#define S_ 64
#define ALL_ 1024     // D*S
#define TWOALL_ 2048
#define M_ 16384      // B*N

typedef __bf16 bf16x8 __attribute__((ext_vector_type(8)));
typedef float floatx4 __attribute__((ext_vector_type(4)));

__device__ __forceinline__ float bf2f(unsigned short u) {
    union { unsigned int i; float f; } v;
    v.i = ((unsigned int)u) << 16;
    return v.f;
}

__device__ __forceinline__ unsigned short f2bf(float f) {
    unsigned int x = __float_as_uint(f);
    unsigned int r = (x + 0x7fffu + ((x >> 16) & 1u)) >> 16;
    return (unsigned short)r;
}

// async global->LDS DMA, 16 B per lane; LDS dest = wave-uniform base + lane*16
__device__ __forceinline__ void load_lds_16(const void* g, void* l) {
    __builtin_amdgcn_global_load_lds(
        (const __attribute__((address_space(1))) void*)g,
        (__attribute__((address_space(3))) void*)l, 16, 0, 0);
}

// ---------------- elementwise fp32 -> bf16 ----------------------------------
__global__ __launch_bounds__(256) void convert_f32_bf16(
    const float* __restrict__ in, unsigned short* __restrict__ out, int n4) {
    int i = blockIdx.x * 256 + threadIdx.x;
    if (i >= n4) return;
    float4 v = *(const float4*)(in + (size_t)i * 4);
    ushort4 o;
    o.x = f2bf(v.x); o.y = f2bf(v.y); o.z = f2bf(v.z); o.w = f2bf(v.w);
    *(ushort4*)(out + (size_t)i * 4) = o;
}

// ---------------- tiled transpose fp32 -> bf16 ------------------------------
__global__ void transpose_f32_bf16(const float* __restrict__ in,
                                   unsigned short* __restrict__ out,
                                   int rows, int cols) {
    __shared__ float tile[32][33];
    int bx = blockIdx.x * 32;
    int by = blockIdx.y * 32;
    int tx = threadIdx.x;
    int ty = threadIdx.y;
    #pragma unroll
    for (int i = 0; i < 32; i += 8)
        tile[ty + i][tx] = in[(size_t)(by + ty + i) * cols + bx + tx];
    __syncthreads();
    #pragma unroll
    for (int i = 0; i < 32; i += 8)
        out[(size_t)(bx + ty + i) * rows + by + tx] = f2bf(tile[tx][ty + i]);
}

// ---------------- MFMA bf16 GEMM: 256x256 8-phase schedule ------------------
// T3+T4+T5 port of the verified 8-phase template (m201-class):
// - BM=BN=256, BK=64, 512 threads = 8 waves (2 in M x 4 in N)
// - per-wave output 128x64 (acc 8x4 floatx4 = 128 VGPR)
// - LDS 128 KiB: As[2][256][64] + Bs[2][256][64], XOR-swizzled (0 conflicts,
//   same layout as previous kernel)
// - staging at half-tile (128 rows = 16 KB) granularity, one half per phase,
//   2 x global_load_lds(16B) per thread per phase
// - counted vmcnt(6) once per K-tile (3 half-tiles in flight); never 0 in loop
// - race-freedom: A frags read fully in phase 1, B frags by phase 3; stores of
//   tile t+2 into buf[t&1] issue only after the post-barrier that follows the
//   lgkmcnt(0) covering that region's reads:
//     phase 1: stage (t+1).B.h2 (other buffer)    reads: A(16) + B n0 (2)
//     phase 2: stage (t+2).A.h1 (A read done ph1) reads: B n1,n2 (4)
//     phase 3: stage (t+2).A.h2                   reads: B n3 (2)
//     phase 4: stage (t+2).B.h1 (B read done ph3) reads: none; vmcnt
#define BM 256
#define BN 256
#define BK 64

#define STAGE_A(buf_, h_, kt_) do { \
    load_lds_16(a_base + (size_t)((h_) * 128) * K + (kt_) * 64, \
                &As[buf_][((h_) * 128 + wave * 16) * 64]); \
    load_lds_16(a_base + (size_t)((h_) * 128 + 8) * K + (kt_) * 64, \
                &As[buf_][((h_) * 128 + wave * 16 + 8) * 64]); \
  } while (0)

#define STAGE_B(buf_, h_, kt_) do { \
    load_lds_16(b_base + (size_t)((h_) * 128) * K + (kt_) * 64, \
                &Bs[buf_][((h_) * 128 + wave * 16) * 64]); \
    load_lds_16(b_base + (size_t)((h_) * 128 + 8) * K + (kt_) * 64, \
                &Bs[buf_][((h_) * 128 + wave * 16 + 8) * 64]); \
  } while (0)

#define LOAD_BF(n_) do { \
    const unsigned short* p_ = Bb + (wn * 64 + (n_) * 16 + lrow) * 64; \
    bfr[n_][0] = *(const bf16x8*)(p_ + ((g0 ^ (lrow & 7)) * 8)); \
    bfr[n_][1] = *(const bf16x8*)(p_ + (((g0 + 4) ^ (lrow & 7)) * 8)); \
  } while (0)

#define MMA16(n_) do { \
    __builtin_amdgcn_s_setprio(1); \
    _Pragma("unroll") \
    for (int kk = 0; kk < 2; ++kk) { \
      _Pragma("unroll") \
      for (int m = 0; m < 8; ++m) \
        acc[m][n_] = __builtin_amdgcn_mfma_f32_16x16x32_bf16( \
            af[m][kk], bfr[n_][kk], acc[m][n_], 0, 0, 0); \
    } \
    __builtin_amdgcn_s_setprio(0); \
  } while (0)

#define POST_BAR() do { \
    __builtin_amdgcn_s_barrier(); \
    __builtin_amdgcn_sched_barrier(0); \
  } while (0)

template <int OUT_BF>
__global__ __launch_bounds__(512, 2) void gemm_bf16(
    const unsigned short* __restrict__ A,   // M x K row-major bf16
    const unsigned short* __restrict__ Bt,  // N x K row-major bf16
    const float* __restrict__ bias,         // N fp32
    void* __restrict__ Cv,                  // M x N row-major
    int M, int N, int K, int gxl, int gypx) {

    __shared__ __align__(16) unsigned short As[2][BM * BK];  // 2 x 32 KB
    __shared__ __align__(16) unsigned short Bs[2][BN * BK];  // 2 x 32 KB

    const int tid  = threadIdx.x;
    const int lane = tid & 63;
    const int wave = tid >> 6;      // 0..7
    const int wm   = wave & 1;      // 2 waves down (128 rows each)
    const int wn   = wave >> 1;     // 4 waves across (64 cols each)

    // XCD swizzle (bijective: grid rows divisible by 8)
    const int flat = blockIdx.x;
    const int xcd  = flat & 7;
    const int slot = flat >> 3;
    const int bx   = slot & ((1 << gxl) - 1);
    const int by   = xcd * gypx + (slot >> gxl);
    const int bm0  = by * BM;
    const int bn0  = bx * BN;

    const int lrow = lane & 15;
    const int g0   = lane >> 4;     // k-group 0..3

    // staging lane map within an 8-row x 64-col chunk (1024 B):
    // lane i -> row i>>3, xor-swizzled col group (i&7)^(i>>3)
    const int srow = lane >> 3;
    const int sg   = (lane & 7) ^ srow;

    const unsigned short* a_base =
        A + (size_t)(bm0 + wave * 16 + srow) * K + sg * 8;
    const unsigned short* b_base =
        Bt + (size_t)(bn0 + wave * 16 + srow) * K + sg * 8;

    floatx4 acc[8][4] = {};
    bf16x8 af[8][2], bfr[4][2];

    const int NTk = K >> 6;   // # K-tiles (16 here)

    // ---- prologue: tile0 fully + tile1 {A.h1, A.h2, B.h1} ----
    STAGE_A(0, 0, 0); STAGE_A(0, 1, 0); STAGE_B(0, 0, 0); STAGE_B(0, 1, 0);
    if (NTk > 1) {
        STAGE_A(1, 0, 1); STAGE_A(1, 1, 1); STAGE_B(1, 0, 1);
        asm volatile("s_waitcnt vmcnt(6)" ::: "memory");
    } else {
        asm volatile("s_waitcnt vmcnt(0)" ::: "memory");
    }
    POST_BAR();

    for (int t = 0; t < NTk; ++t) {
        const int buf = t & 1;
        const unsigned short* Ab = As[buf];
        const unsigned short* Bb = Bs[buf];

        // ===== phase 1: read all A frags + B n0; stage (t+1).B.h2 =====
        #pragma unroll
        for (int m = 0; m < 8; ++m) {
            const unsigned short* p_ = Ab + (wm * 128 + m * 16 + lrow) * 64;
            af[m][0] = *(const bf16x8*)(p_ + ((g0 ^ (lrow & 7)) * 8));
            af[m][1] = *(const bf16x8*)(p_ + (((g0 + 4) ^ (lrow & 7)) * 8));
        }
        LOAD_BF(0);
        if (t + 1 < NTk) STAGE_B((t + 1) & 1, 1, t + 1);
        __builtin_amdgcn_s_barrier();
        asm volatile("s_waitcnt lgkmcnt(0)" ::: "memory");
        MMA16(0);
        POST_BAR();

        // ===== phase 2: read B n1,n2; stage (t+2).A.h1 =====
        LOAD_BF(1);
        LOAD_BF(2);
        if (t + 2 < NTk) STAGE_A(buf, 0, t + 2);
        __builtin_amdgcn_s_barrier();
        asm volatile("s_waitcnt lgkmcnt(0)" ::: "memory");
        MMA16(1);
        POST_BAR();

        // ===== phase 3: read B n3; stage (t+2).A.h2 =====
        LOAD_BF(3);
        if (t + 2 < NTk) STAGE_A(buf, 1, t + 2);
        __builtin_amdgcn_s_barrier();
        asm volatile("s_waitcnt lgkmcnt(0)" ::: "memory");
        MMA16(2);
        POST_BAR();

        // ===== phase 4: no reads; stage (t+2).B.h1; counted vmcnt =====
        if (t + 2 < NTk) STAGE_B(buf, 0, t + 2);
        __builtin_amdgcn_s_barrier();
        MMA16(3);
        if (t + 2 < NTk) {
            asm volatile("s_waitcnt vmcnt(6)" ::: "memory");
        } else if (t + 1 < NTk) {
            asm volatile("s_waitcnt vmcnt(0)" ::: "memory");
        }
        POST_BAR();
    }

    // C/D layout (m89-verified): col = lane&15, row = (lane>>4)*4 + r
    #pragma unroll
    for (int n = 0; n < 4; ++n) {
        int col = bn0 + wn * 64 + n * 16 + (lane & 15);
        float bv = bias[col];
        #pragma unroll
        for (int m = 0; m < 8; ++m) {
            #pragma unroll
            for (int r = 0; r < 4; ++r) {
                int row = bm0 + wm * 128 + m * 16 + (lane >> 4) * 4 + r;
                float v = acc[m][n][r] + bv;
                if (OUT_BF)
                    ((unsigned short*)Cv)[(size_t)row * N + col] = f2bf(v);
                else
                    ((float*)Cv)[(size_t)row * N + col] = v;
            }
        }
    }
}

// ---------------- middle: softmax + banded accumulation (bf16 P) ------------
__global__ __launch_bounds__(256) void middle_kernel(
    const unsigned short* __restrict__ P,
    unsigned short* __restrict__ A2) {

    int idx = blockIdx.x * 256 + threadIdx.x;
    int s   = idx & 63;
    int r   = idx >> 6;            // b*N + n
    int n   = r & (N_ - 1);
    const int t = n & (D_ - 1);
    const int c = n >> 4;

    const unsigned short* Lp = P + (size_t)r * TWOALL_ + s;
    float w[16];
    float mx = -1e30f;
    #pragma unroll
    for (int j = 0; j < 16; ++j) {
        w[j] = bf2f(Lp[j * S_]);
        mx = fmaxf(mx, w[j]);
    }
    float sum = 0.f;
    #pragma unroll
    for (int j = 0; j < 16; ++j) {
        w[j] = __expf(w[j] - mx);
        sum += w[j];
    }
    float inv = 1.0f / sum;

    float q[16];
    #pragma unroll
    for (int d = 0; d < 16; ++d) q[d] = 0.f;

    #pragma unroll
    for (int i = 0; i < 15; ++i) {
        int np = n + i + 1;
        if (np >= N_) np -= N_;
        int b = r >> 12;
        const unsigned short* Rp = P + (((size_t)(b * N_ + np)) * 2 + 1) * ALL_ + s;
        #pragma unroll
        for (int k = 0; k < 15 - i; ++k) {
            q[i + k + 1] += w[i] * bf2f(Rp[k * S_]);
        }
    }

    unsigned short* out = A2 + (size_t)r * ALL_ + s;
    bool last = (c == (N_ / D_) - 1);
    #pragma unroll
    for (int d = 0; d < 16; ++d) {
        float v = (d == 0) ? 0.f : q[d] * inv;
        if (last && (t + d >= D_)) v = 0.f;
        out[d * S_] = f2bf(v);
    }
}

// ---------------- launch -----------------------------------------------------
extern "C" void kernel_launch(void* const* d_in, const int* in_sizes, int n_in,
                              void* d_out, int out_size, void* d_ws, size_t ws_size,
                              hipStream_t stream) {
    const float* x   = (const float*)d_in[0];
    const float* W_r = (const float*)d_in[1];
    const float* b_r = (const float*)d_in[2];
    const float* W_w = (const float*)d_in[3];
    const float* b_w = (const float*)d_in[4];
    float* out = (float*)d_out;

    // workspace: P bf16 67.1MB | xbf 33.6MB | A2 33.6MB | WrT 4.2MB | WwT 2.1MB
    unsigned short* ws  = (unsigned short*)d_ws;
    unsigned short* P   = ws;
    unsigned short* xbf = P   + (size_t)M_ * TWOALL_;
    unsigned short* A2  = xbf + (size_t)M_ * ALL_;
    unsigned short* WrT = A2  + (size_t)M_ * ALL_;
    unsigned short* WwT = WrT + (size_t)TWOALL_ * PD_;

    convert_f32_bf16<<<dim3((M_ * PD_ / 4 + 255) / 256), 256, 0, stream>>>(
        x, xbf, M_ * PD_ / 4);

    dim3 tb(32, 8);
    transpose_f32_bf16<<<dim3(TWOALL_ / 32, PD_ / 32), tb, 0, stream>>>(W_r, WrT, PD_, TWOALL_);
    transpose_f32_bf16<<<dim3(ALL_ / 32, PD_ / 32), tb, 0, stream>>>(W_w, WwT, PD_, ALL_);

    // GEMM1: P(bf16) = x @ W_r + b_r  (M=16384, N=2048, K=1024)
    // grid 8x64 tiles -> 512 blocks, XCD swizzle gxl=3, 8 row-tiles per XCD
    gemm_bf16<1><<<dim3((TWOALL_ / BN) * (M_ / BM)), 512, 0, stream>>>(
        xbf, WrT, b_r, P, M_, TWOALL_, PD_, 3, (M_ / BM) / 8);

    middle_kernel<<<dim3((B_ * N_ * S_) / 256), 256, 0, stream>>>(P, A2);

    // GEMM2: out(f32) = A2 @ W_w + b_w  (M=16384, N=1024, K=1024)
    // grid 4x64 tiles -> 256 blocks, gxl=2
    gemm_bf16<0><<<dim3((ALL_ / BN) * (M_ / BM)), 512, 0, stream>>>(
        A2, WwT, b_w, out, M_, ALL_, PD_, 2, (M_ / BM) / 8);
}